// Round 3
// baseline (106.157 us; speedup 1.0000x reference)
//
#include <hip/hip_runtime.h>

// Fully fused single launch.  Round-3: decouple round-2's confounded vars.
//   - 256 blocks (1/CU) -> table built exactly once per CU (round-1's best).
//   - 512 threads/block (8 waves/CU = 2 waves/SIMD) -> 2x latency hiding in
//     the compute loop vs round-1's 1 wave/SIMD.
//   - 2 rows/thread (xv[2][4] = 32 VGPR) -> no spill risk; x loads issued at
//     kernel entry, hidden under the table build.
// Build matmul phases run on t<256 (same math as before); fold phases stride
// over all 512 threads.

__device__ __forceinline__ float layer_angle(const float* __restrict__ w,
                                             int l, int idx) {
    float ang = 0.f;
    #pragma unroll
    for (int g = 0; g < 4; ++g) {
        int cb = (idx >> (3 - g)) & 1;                 // control = wire g
        int tb = (idx >> (3 - ((g + 1) & 3))) & 1;     // target  = wire (g+1)%4
        if (cb) ang += (tb ? 0.5f : -0.5f) * w[l * 4 + g];
    }
    return ang;
}

__device__ __forceinline__ float2 f2fmas(float2 a, float b, float2 c) {
    return make_float2(fmaf(a.x, b, c.x), fmaf(a.y, b, c.y));
}
__device__ __forceinline__ float2 f2fma(float2 a, float2 b, float2 c) {
    return make_float2(fmaf(a.x, b.x, c.x), fmaf(a.y, b.y, c.y));
}
__device__ __forceinline__ float2 f2add(float2 a, float2 b) {
    return make_float2(a.x + b.x, a.y + b.y);
}

// Evaluate both rows (packed .x/.y) against the 4x9x12 padded table.
__device__ __forceinline__ void compute_pair(
    const float4 (&xv)[2][4],
    const float (&tabs)[4][9][12],
    float* __restrict__ out,
    int base, int nrows, int t)
{
    float2 d = make_float2(0.f, 0.f);

    #pragma unroll
    for (int s = 0; s < 4; ++s) {
        float2 C0, S0, C1v, S1, C2, S2, C3, S3;
        #pragma unroll
        for (int r = 0; r < 2; ++r) {
            const int lo = (s >> 1) * 2;
            float4 va = xv[r][lo], vb = xv[r][lo + 1];
            float a0, a1, a2, a3;
            if (s & 1) { a0 = va.z; a1 = va.w; a2 = vb.z; a3 = vb.w; }
            else       { a0 = va.x; a1 = va.y; a2 = vb.x; a3 = vb.y; }
            float c, sn;
            __sincosf(a0, &sn, &c);
            if (r) { C0.y = c; S0.y = sn; } else { C0.x = c; S0.x = sn; }
            __sincosf(a1, &sn, &c);
            if (r) { C1v.y = c; S1.y = sn; } else { C1v.x = c; S1.x = sn; }
            __sincosf(a2, &sn, &c);
            if (r) { C2.y = c; S2.y = sn; } else { C2.x = c; S2.x = sn; }
            __sincosf(a3, &sn, &c);
            if (r) { C3.y = c; S3.y = sn; } else { C3.x = c; S3.x = sn; }
        }

        #pragma unroll
        for (int t0 = 0; t0 < 3; ++t0) {
            float2 acc = make_float2(0.f, 0.f);
            #pragma unroll
            for (int t1 = 0; t1 < 3; ++t1) {
                const float* tp = &tabs[s][t0 * 3 + t1][0];
                float4 q0 = *(const float4*)tp;        // k0..k3
                float4 q1 = *(const float4*)(tp + 4);  // k4..k7
                float  k8 = tp[8];
                float2 u0 = f2fmas(S3, q0.z,
                             f2fmas(C3, q0.y, make_float2(q0.x, q0.x)));
                float2 u1 = f2fmas(S3, q1.y,
                             f2fmas(C3, q1.x, make_float2(q0.w, q0.w)));
                float2 u2 = f2fmas(S3, k8,
                             f2fmas(C3, q1.w, make_float2(q1.z, q1.z)));
                float2 a1v = f2fma(S2, u2, f2fma(C2, u1, u0));
                if      (t1 == 0) acc = f2add(acc, a1v);
                else if (t1 == 1) acc = f2fma(C1v, a1v, acc);
                else              acc = f2fma(S1,  a1v, acc);
            }
            if      (t0 == 0) d = f2add(d, acc);
            else if (t0 == 1) d = f2fma(C0, acc, d);
            else              d = f2fma(S0, acc, d);
        }
    }

    #pragma unroll
    for (int r = 0; r < 2; ++r) {
        int row = base + r * 512 + t;
        if (row < nrows) {
            float dv = r ? d.y : d.x;
            float p0 = 1.f / (1.f + __expf(-dv));
            *(float2*)(out + (size_t)row * 2) = make_float2(p0, 1.f - p0);
        }
    }
}

__global__ __launch_bounds__(512) void fused_qcircuit(
    const float* __restrict__ x,
    const float* __restrict__ weights,
    const float* __restrict__ lin_w,
    const float* __restrict__ lin_b,
    float* __restrict__ out,
    int nrows)
{
    __shared__ float2 U1[256], U2[256], U[256];   // row-major [i*16+j]
    __shared__ float zeta[4][16];
    __shared__ float G[4][256];
    __shared__ float A[4][3][64];
    __shared__ float B[4][9][16];
    __shared__ float C1[4][27][4];
    __shared__ __align__(16) float tabs[4][9][12];  // [s][t0*3+t1][t2*3+t3] pad 12

    int t = threadIdx.x;           // 0..511
    int i = t >> 4, j = t & 15;    // valid for t<256 build phases

    // ---- issue x loads at entry: hidden under the table build ----
    int base = blockIdx.x * 1024;
    float4 xv[2][4];
    #pragma unroll
    for (int r = 0; r < 2; ++r) {
        int row = base + r * 512 + t;
        int rc = row < nrows ? row : 0;
        const float4* xp = (const float4*)(x + (size_t)rc * 16);
        xv[r][0] = xp[0]; xv[r][1] = xp[1]; xv[r][2] = xp[2]; xv[r][3] = xp[3];
    }
    float bias = lin_b[0] - lin_b[1];

    // ---- table build: matmul phases on t<256, folds on all 512 ----
    if (t < 256) {
        // U1 = Hhat * D0   (Hhat[i][j] = (-1)^popc(i&j), unnormalized)
        float sgn = (__popc(i & j) & 1) ? -1.f : 1.f;
        float a = layer_angle(weights, 0, j);
        U1[t] = make_float2(sgn * __cosf(a), sgn * __sinf(a));
    }
    // zeta[s][k] = sum_w (lin_w[0,4s+w]-lin_w[1,4s+w]) * (-1)^{bit(3-w) of k}
    if (t < 64) {
        int s = t >> 4, k = t & 15;
        float z = 0.f;
        #pragma unroll
        for (int w = 0; w < 4; ++w) {
            float sg = ((k >> (3 - w)) & 1) ? -1.f : 1.f;
            z += (lin_w[s * 4 + w] - lin_w[16 + s * 4 + w]) * sg;
        }
        zeta[s][k] = z;
    }
    __syncthreads();
    // U2 = Hhat * D1 * U1
    if (t < 256) {
        float ar = 0.f, ai = 0.f;
        for (int k = 0; k < 16; ++k) {
            float sgn = (__popc(i & k) & 1) ? -1.f : 1.f;
            float a = layer_angle(weights, 1, k);
            float cr = sgn * __cosf(a), ci = sgn * __sinf(a);
            float2 u = U1[k * 16 + j];
            ar += cr * u.x - ci * u.y;
            ai += cr * u.y + ci * u.x;
        }
        U2[t] = make_float2(ar, ai);
    }
    __syncthreads();
    // U = Hhat * D2 * U2
    if (t < 256) {
        float ar = 0.f, ai = 0.f;
        for (int k = 0; k < 16; ++k) {
            float sgn = (__popc(i & k) & 1) ? -1.f : 1.f;
            float a = layer_angle(weights, 2, k);
            float cr = sgn * __cosf(a), ci = sgn * __sinf(a);
            float2 u = U2[k * 16 + j];
            ar += cr * u.x - ci * u.y;
            ai += cr * u.y + ci * u.x;
        }
        U[t] = make_float2(ar, ai);
    }
    __syncthreads();
    // G[s][i*16+j] = sum_k zeta[s][k] * Re(conj(U[k,i]) U[k,j])
    if (t < 256) {
        float g[4] = {0, 0, 0, 0};
        for (int k = 0; k < 16; ++k) {
            float2 uki = U[k * 16 + i], ukj = U[k * 16 + j];
            float p = uki.x * ukj.x + uki.y * ukj.y;
            #pragma unroll
            for (int s = 0; s < 4; ++s) g[s] += zeta[s][k] * p;
        }
        #pragma unroll
        for (int s = 0; s < 4; ++s) G[s][t] = g[s];
    }
    __syncthreads();
    // Fold wire3 (LSB): A[s][t3][ih*8+jh]
    for (int e = t; e < 768; e += 512) {
        int m = e / 192, r = e % 192;
        int t3 = r / 64, q = r % 64;
        int ih = q >> 3, jh = q & 7;
        float g00 = G[m][(ih * 2 + 0) * 16 + jh * 2 + 0];
        float g01 = G[m][(ih * 2 + 0) * 16 + jh * 2 + 1];
        float g10 = G[m][(ih * 2 + 1) * 16 + jh * 2 + 0];
        float g11 = G[m][(ih * 2 + 1) * 16 + jh * 2 + 1];
        A[m][t3][q] = (t3 == 0) ? g00 + g11 : (t3 == 1) ? g00 - g11 : g01 + g10;
    }
    __syncthreads();
    // Fold wire2: B[s][t2*3+t3][ih*4+jh]
    for (int e = t; e < 576; e += 512) {
        int m = e / 144, r = e % 144;
        int t2 = r / 48; r %= 48;
        int t3 = r / 16, q = r % 16;
        int ih = q >> 2, jh = q & 3;
        float a00 = A[m][t3][(ih * 2 + 0) * 8 + jh * 2 + 0];
        float a01 = A[m][t3][(ih * 2 + 0) * 8 + jh * 2 + 1];
        float a10 = A[m][t3][(ih * 2 + 1) * 8 + jh * 2 + 0];
        float a11 = A[m][t3][(ih * 2 + 1) * 8 + jh * 2 + 1];
        B[m][t2 * 3 + t3][q] = (t2 == 0) ? a00 + a11
                             : (t2 == 1) ? a00 - a11 : a01 + a10;
    }
    __syncthreads();
    // Fold wire1: C1[s][t1*9+t2*3+t3][ih*2+jh]
    for (int e = t; e < 432; e += 512) {
        int m = e / 108, r = e % 108;
        int t1 = r / 36; r %= 36;
        int t23 = r / 4, q = r % 4;
        int ih = q >> 1, jh = q & 1;
        float b00 = B[m][t23][(ih * 2 + 0) * 4 + jh * 2 + 0];
        float b01 = B[m][t23][(ih * 2 + 0) * 4 + jh * 2 + 1];
        float b10 = B[m][t23][(ih * 2 + 1) * 4 + jh * 2 + 0];
        float b11 = B[m][t23][(ih * 2 + 1) * 4 + jh * 2 + 1];
        C1[m][t1 * 9 + t23][q] = (t1 == 0) ? b00 + b11
                               : (t1 == 1) ? b00 - b11 : b01 + b10;
    }
    __syncthreads();
    // Fold wire0 + write padded tiles.  Scale: (1/64)^2 H-norm, (1/2)^4
    // half-angle basis.  lin_b difference folded into [0][0][0].
    {
        const float scale = 1.f / 65536.f;
        for (int e = t; e < 324; e += 512) {
            int m = e / 81, r = e % 81;
            int t0 = r / 27, t123 = r % 27;
            const float* c = C1[m][t123];
            float v = (t0 == 0) ? c[0] + c[3] : (t0 == 1) ? c[0] - c[3]
                                              : c[1] + c[2];
            float val = v * scale;
            if (e == 0) val += bias;
            int t1 = t123 / 9, k = t123 % 9;
            tabs[m][t0 * 3 + t1][k] = val;
        }
    }
    __syncthreads();

    // ---- batch compute: 2 rows/thread, float2-packed, 2 waves/SIMD ----
    compute_pair(xv, tabs, out, base, nrows, t);

    // grid-stride fallback (dead when grid covers nrows exactly)
    for (base += gridDim.x * 1024; base < nrows; base += gridDim.x * 1024) {
        #pragma unroll
        for (int r = 0; r < 2; ++r) {
            int row = base + r * 512 + t;
            int rc = row < nrows ? row : 0;
            const float4* xp = (const float4*)(x + (size_t)rc * 16);
            xv[r][0] = xp[0]; xv[r][1] = xp[1]; xv[r][2] = xp[2]; xv[r][3] = xp[3];
        }
        compute_pair(xv, tabs, out, base, nrows, t);
    }
}

extern "C" void kernel_launch(void* const* d_in, const int* in_sizes, int n_in,
                              void* d_out, int out_size, void* d_ws, size_t ws_size,
                              hipStream_t stream) {
    const float* x       = (const float*)d_in[0];
    const float* weights = (const float*)d_in[1];
    const float* lin_w   = (const float*)d_in[2];
    const float* lin_b   = (const float*)d_in[3];
    float* out = (float*)d_out;

    int nrows = in_sizes[0] / 16;
    int grid = (nrows + 1023) / 1024;
    if (grid < 1) grid = 1;
    fused_qcircuit<<<grid, 512, 0, stream>>>(x, weights, lin_w, lin_b, out, nrows);
}

// Round 4
// 76.455 us; speedup vs baseline: 1.3885x; 1.3885x over previous
//
#include <hip/hip_runtime.h>

// Round-4: two-kernel split, occupancy-first.
//   K1 precompute (1 block): builds the 4x9x12 padded difference table
//      (bias folded into [0][0][0]) into ws.  ~2us, off the hot path.
//   K2 main: 1024 blocks x 256 threads, 1 row/thread, 4 waves/SIMD TLP.
//      Per-block setup = 108 float4 LDS copy + 1 barrier (~200 cyc).
//      Trig computed per-s (8 live values) -> ~60 VGPR, no spill.
// Round-3's lesson: __launch_bounds__(512) + xv-across-build = 128-VGPR cap
// + 75MB scratch spill (WRITE_SIZE 76800KB vs 2.1MB ideal).  This version
// keeps peak pressure ~60 VGPR and gets latency hiding from TLP instead of
// per-thread batching.

__device__ __forceinline__ float layer_angle(const float* __restrict__ w,
                                             int l, int idx) {
    float ang = 0.f;
    #pragma unroll
    for (int g = 0; g < 4; ++g) {
        int cb = (idx >> (3 - g)) & 1;                 // control = wire g
        int tb = (idx >> (3 - ((g + 1) & 3))) & 1;     // target  = wire (g+1)%4
        if (cb) ang += (tb ? 0.5f : -0.5f) * w[l * 4 + g];
    }
    return ang;
}

__global__ __launch_bounds__(256) void precompute_tensors(
    const float* __restrict__ weights,
    const float* __restrict__ lin_w,
    const float* __restrict__ lin_b,
    float* __restrict__ ws)     // [4][9][12] padded, bias in [0][0][0]
{
    __shared__ float2 U1[256], U2[256], U[256];   // row-major [i*16+j]
    __shared__ float zeta[4][16];
    __shared__ float G[4][256];
    __shared__ float A[4][3][64];
    __shared__ float B[4][9][16];
    __shared__ float C1[4][27][4];
    int t = threadIdx.x;
    int i = t >> 4, j = t & 15;

    // U1 = Hhat * D0   (Hhat[i][j] = (-1)^popc(i&j), unnormalized)
    {
        float sgn = (__popc(i & j) & 1) ? -1.f : 1.f;
        float a = layer_angle(weights, 0, j);
        U1[t] = make_float2(sgn * __cosf(a), sgn * __sinf(a));
    }
    // zeta[s][k] = sum_w (lin_w[0,4s+w]-lin_w[1,4s+w]) * (-1)^{bit(3-w) of k}
    if (t < 64) {
        int s = t >> 4, k = t & 15;
        float z = 0.f;
        #pragma unroll
        for (int w = 0; w < 4; ++w) {
            float sg = ((k >> (3 - w)) & 1) ? -1.f : 1.f;
            z += (lin_w[s * 4 + w] - lin_w[16 + s * 4 + w]) * sg;
        }
        zeta[s][k] = z;
    }
    __syncthreads();
    // U2 = Hhat * D1 * U1
    {
        float ar = 0.f, ai = 0.f;
        for (int k = 0; k < 16; ++k) {
            float sgn = (__popc(i & k) & 1) ? -1.f : 1.f;
            float a = layer_angle(weights, 1, k);
            float cr = sgn * __cosf(a), ci = sgn * __sinf(a);
            float2 u = U1[k * 16 + j];
            ar += cr * u.x - ci * u.y;
            ai += cr * u.y + ci * u.x;
        }
        U2[t] = make_float2(ar, ai);
    }
    __syncthreads();
    // U = Hhat * D2 * U2
    {
        float ar = 0.f, ai = 0.f;
        for (int k = 0; k < 16; ++k) {
            float sgn = (__popc(i & k) & 1) ? -1.f : 1.f;
            float a = layer_angle(weights, 2, k);
            float cr = sgn * __cosf(a), ci = sgn * __sinf(a);
            float2 u = U2[k * 16 + j];
            ar += cr * u.x - ci * u.y;
            ai += cr * u.y + ci * u.x;
        }
        U[t] = make_float2(ar, ai);
    }
    __syncthreads();
    // G[s][i*16+j] = sum_k zeta[s][k] * Re(conj(U[k,i]) U[k,j])
    {
        float g[4] = {0, 0, 0, 0};
        for (int k = 0; k < 16; ++k) {
            float2 uki = U[k * 16 + i], ukj = U[k * 16 + j];
            float p = uki.x * ukj.x + uki.y * ukj.y;
            #pragma unroll
            for (int s = 0; s < 4; ++s) g[s] += zeta[s][k] * p;
        }
        #pragma unroll
        for (int s = 0; s < 4; ++s) G[s][t] = g[s];
    }
    __syncthreads();
    // Fold wire3 (LSB): A[s][t3][ih*8+jh]
    for (int e = t; e < 768; e += 256) {
        int m = e / 192, r = e % 192;
        int t3 = r / 64, q = r % 64;
        int ih = q >> 3, jh = q & 7;
        float g00 = G[m][(ih * 2 + 0) * 16 + jh * 2 + 0];
        float g01 = G[m][(ih * 2 + 0) * 16 + jh * 2 + 1];
        float g10 = G[m][(ih * 2 + 1) * 16 + jh * 2 + 0];
        float g11 = G[m][(ih * 2 + 1) * 16 + jh * 2 + 1];
        A[m][t3][q] = (t3 == 0) ? g00 + g11 : (t3 == 1) ? g00 - g11 : g01 + g10;
    }
    __syncthreads();
    // Fold wire2: B[s][t2*3+t3][ih*4+jh]
    for (int e = t; e < 576; e += 256) {
        int m = e / 144, r = e % 144;
        int t2 = r / 48; r %= 48;
        int t3 = r / 16, q = r % 16;
        int ih = q >> 2, jh = q & 3;
        float a00 = A[m][t3][(ih * 2 + 0) * 8 + jh * 2 + 0];
        float a01 = A[m][t3][(ih * 2 + 0) * 8 + jh * 2 + 1];
        float a10 = A[m][t3][(ih * 2 + 1) * 8 + jh * 2 + 0];
        float a11 = A[m][t3][(ih * 2 + 1) * 8 + jh * 2 + 1];
        B[m][t2 * 3 + t3][q] = (t2 == 0) ? a00 + a11
                             : (t2 == 1) ? a00 - a11 : a01 + a10;
    }
    __syncthreads();
    // Fold wire1: C1[s][t1*9+t2*3+t3][ih*2+jh]
    for (int e = t; e < 432; e += 256) {
        int m = e / 108, r = e % 108;
        int t1 = r / 36; r %= 36;
        int t23 = r / 4, q = r % 4;
        int ih = q >> 1, jh = q & 1;
        float b00 = B[m][t23][(ih * 2 + 0) * 4 + jh * 2 + 0];
        float b01 = B[m][t23][(ih * 2 + 0) * 4 + jh * 2 + 1];
        float b10 = B[m][t23][(ih * 2 + 1) * 4 + jh * 2 + 0];
        float b11 = B[m][t23][(ih * 2 + 1) * 4 + jh * 2 + 1];
        C1[m][t1 * 9 + t23][q] = (t1 == 0) ? b00 + b11
                               : (t1 == 1) ? b00 - b11 : b01 + b10;
    }
    __syncthreads();
    // Fold wire0 + write padded [4][9][12] layout.  Scale: (1/64)^2 H-norm,
    // (1/2)^4 half-angle basis.  lin_b difference folded into element 0.
    {
        const float scale = 1.f / 65536.f;
        float bias = lin_b[0] - lin_b[1];
        for (int e = t; e < 324; e += 256) {
            int m = e / 81, r = e % 81;
            int t0 = r / 27, t123 = r % 27;
            const float* c = C1[m][t123];
            float v = (t0 == 0) ? c[0] + c[3] : (t0 == 1) ? c[0] - c[3]
                                              : c[1] + c[2];
            float val = v * scale;
            if (e == 0) val += bias;
            int t1 = t123 / 9, k = t123 % 9;
            ws[(m * 9 + t0 * 3 + t1) * 12 + k] = val;
        }
    }
}

__global__ __launch_bounds__(256) void qcircuit_kernel(
    const float* __restrict__ x,
    const float* __restrict__ tab,   // [4][9][12] padded
    float* __restrict__ out,
    int nrows)
{
    __shared__ __align__(16) float tabs[4][9][12];   // 432 floats = 1728 B

    int t = threadIdx.x;
    // per-block table copy: 108 float4
    if (t < 108) ((float4*)tabs)[t] = ((const float4*)tab)[t];

    int b = blockIdx.x * blockDim.x + t;
    int bc = b < nrows ? b : 0;
    const float4* xp = (const float4*)(x + (size_t)bc * 16);
    float4 xa = xp[0], xb = xp[1], xc = xp[2], xd = xp[3];
    float xs[16] = {xa.x, xa.y, xa.z, xa.w, xb.x, xb.y, xb.z, xb.w,
                    xc.x, xc.y, xc.z, xc.w, xd.x, xd.y, xd.z, xd.w};
    __syncthreads();

    float d = 0.f;
    #pragma unroll
    for (int s = 0; s < 4; ++s) {
        const int b0 = ((s >> 1) << 3) + ((s & 1) << 1);
        // wires 0,1,2,3 of circuit s -> x indices b0, b0+1, b0+4, b0+5
        float C0, S0, C1v, S1, C2, S2, C3, S3;
        __sincosf(xs[b0],     &S0,  &C0);
        __sincosf(xs[b0 + 1], &S1,  &C1v);
        __sincosf(xs[b0 + 4], &S2,  &C2);
        __sincosf(xs[b0 + 5], &S3,  &C3);
        #pragma unroll
        for (int t0 = 0; t0 < 3; ++t0) {
            float acc = 0.f;
            #pragma unroll
            for (int t1 = 0; t1 < 3; ++t1) {
                const float* tp = &tabs[s][t0 * 3 + t1][0];
                float4 q0 = *(const float4*)tp;        // k0..k3
                float4 q1 = *(const float4*)(tp + 4);  // k4..k7
                float  k8 = tp[8];
                float u0 = fmaf(S3, q0.z, fmaf(C3, q0.y, q0.x));
                float u1 = fmaf(S3, q1.y, fmaf(C3, q1.x, q0.w));
                float u2 = fmaf(S3, k8,   fmaf(C3, q1.w, q1.z));
                float a1 = fmaf(S2, u2, fmaf(C2, u1, u0));
                acc = (t1 == 0) ? acc + a1
                    : (t1 == 1) ? fmaf(C1v, a1, acc)
                                : fmaf(S1,  a1, acc);
            }
            d = (t0 == 0) ? d + acc
              : (t0 == 1) ? fmaf(C0, acc, d)
                          : fmaf(S0, acc, d);
        }
    }

    if (b < nrows) {
        // bias already folded into tabs[0][0][0]; softmax over 2 = sigmoid
        float p0 = 1.f / (1.f + __expf(-d));
        *(float2*)(out + (size_t)b * 2) = make_float2(p0, 1.f - p0);
    }
}

extern "C" void kernel_launch(void* const* d_in, const int* in_sizes, int n_in,
                              void* d_out, int out_size, void* d_ws, size_t ws_size,
                              hipStream_t stream) {
    const float* x       = (const float*)d_in[0];
    const float* weights = (const float*)d_in[1];
    const float* lin_w   = (const float*)d_in[2];
    const float* lin_b   = (const float*)d_in[3];
    float* out = (float*)d_out;
    float* ws  = (float*)d_ws;

    int nrows = in_sizes[0] / 16;

    precompute_tensors<<<1, 256, 0, stream>>>(weights, lin_w, lin_b, ws);

    int block = 256;
    int grid = (nrows + block - 1) / block;
    qcircuit_kernel<<<grid, block, 0, stream>>>(x, ws, out, nrows);
}

// Round 5
// 73.859 us; speedup vs baseline: 1.4373x; 1.0352x over previous
//
#include <hip/hip_runtime.h>

// Round-5: single fused kernel, 256 blocks x 1024 threads (1 block/CU,
// 4 waves/SIMD).  Table built ONCE per CU (threads 0-255 run the matmul
// phases, all 1024 stride the folds) -> replaces the ~3us serial K1 + launch
// gap with ~1.5us of parallel per-CU build.  Compute loop identical to
// round-4's K2 (best measured), reading tabs directly from LDS.
// VGPR budget: 1 row/thread, x (16 VGPR) issued at entry; peak ~70 < 128 cap.

__device__ __forceinline__ float layer_angle(const float* __restrict__ w,
                                             int l, int idx) {
    float ang = 0.f;
    #pragma unroll
    for (int g = 0; g < 4; ++g) {
        int cb = (idx >> (3 - g)) & 1;                 // control = wire g
        int tb = (idx >> (3 - ((g + 1) & 3))) & 1;     // target  = wire (g+1)%4
        if (cb) ang += (tb ? 0.5f : -0.5f) * w[l * 4 + g];
    }
    return ang;
}

__global__ __launch_bounds__(1024) void fused_qcircuit(
    const float* __restrict__ x,
    const float* __restrict__ weights,
    const float* __restrict__ lin_w,
    const float* __restrict__ lin_b,
    float* __restrict__ out,
    int nrows)
{
    __shared__ float2 U1[256], U2[256], U[256];   // row-major [i*16+j]
    __shared__ float zeta[4][16];
    __shared__ float G[4][256];
    __shared__ float A[4][3][64];
    __shared__ float B[4][9][16];
    __shared__ float C1[4][27][4];
    __shared__ __align__(16) float tabs[4][9][12];  // [s][t0*3+t1][k] pad 12

    int t = threadIdx.x;            // 0..1023
    int i = t >> 4, j = t & 15;     // build-phase coords (t<256 only)

    // ---- x load at entry: 16 VGPR, latency hidden under the build ----
    int b = blockIdx.x * blockDim.x + t;
    int bc = b < nrows ? b : 0;
    const float4* xp = (const float4*)(x + (size_t)bc * 16);
    float4 xa = xp[0], xb = xp[1], xc = xp[2], xd = xp[3];

    // ---- table build: matmuls on t<256, folds on all 1024 ----
    if (t < 256) {
        // U1 = Hhat * D0   (Hhat[i][j] = (-1)^popc(i&j), unnormalized)
        float sgn = (__popc(i & j) & 1) ? -1.f : 1.f;
        float a = layer_angle(weights, 0, j);
        U1[t] = make_float2(sgn * __cosf(a), sgn * __sinf(a));
    }
    // zeta[s][k] = sum_w (lin_w[0,4s+w]-lin_w[1,4s+w]) * (-1)^{bit(3-w) of k}
    if (t < 64) {
        int s = t >> 4, k = t & 15;
        float z = 0.f;
        #pragma unroll
        for (int w = 0; w < 4; ++w) {
            float sg = ((k >> (3 - w)) & 1) ? -1.f : 1.f;
            z += (lin_w[s * 4 + w] - lin_w[16 + s * 4 + w]) * sg;
        }
        zeta[s][k] = z;
    }
    __syncthreads();
    // U2 = Hhat * D1 * U1
    if (t < 256) {
        float ar = 0.f, ai = 0.f;
        for (int k = 0; k < 16; ++k) {
            float sgn = (__popc(i & k) & 1) ? -1.f : 1.f;
            float a = layer_angle(weights, 1, k);
            float cr = sgn * __cosf(a), ci = sgn * __sinf(a);
            float2 u = U1[k * 16 + j];
            ar += cr * u.x - ci * u.y;
            ai += cr * u.y + ci * u.x;
        }
        U2[t] = make_float2(ar, ai);
    }
    __syncthreads();
    // U = Hhat * D2 * U2
    if (t < 256) {
        float ar = 0.f, ai = 0.f;
        for (int k = 0; k < 16; ++k) {
            float sgn = (__popc(i & k) & 1) ? -1.f : 1.f;
            float a = layer_angle(weights, 2, k);
            float cr = sgn * __cosf(a), ci = sgn * __sinf(a);
            float2 u = U2[k * 16 + j];
            ar += cr * u.x - ci * u.y;
            ai += cr * u.y + ci * u.x;
        }
        U[t] = make_float2(ar, ai);
    }
    __syncthreads();
    // G[s][i*16+j] = sum_k zeta[s][k] * Re(conj(U[k,i]) U[k,j])
    if (t < 256) {
        float g[4] = {0, 0, 0, 0};
        for (int k = 0; k < 16; ++k) {
            float2 uki = U[k * 16 + i], ukj = U[k * 16 + j];
            float p = uki.x * ukj.x + uki.y * ukj.y;
            #pragma unroll
            for (int s = 0; s < 4; ++s) g[s] += zeta[s][k] * p;
        }
        #pragma unroll
        for (int s = 0; s < 4; ++s) G[s][t] = g[s];
    }
    __syncthreads();
    // Fold wire3 (LSB): A[s][t3][ih*8+jh]
    for (int e = t; e < 768; e += 1024) {
        int m = e / 192, r = e % 192;
        int t3 = r / 64, q = r % 64;
        int ih = q >> 3, jh = q & 7;
        float g00 = G[m][(ih * 2 + 0) * 16 + jh * 2 + 0];
        float g01 = G[m][(ih * 2 + 0) * 16 + jh * 2 + 1];
        float g10 = G[m][(ih * 2 + 1) * 16 + jh * 2 + 0];
        float g11 = G[m][(ih * 2 + 1) * 16 + jh * 2 + 1];
        A[m][t3][q] = (t3 == 0) ? g00 + g11 : (t3 == 1) ? g00 - g11 : g01 + g10;
    }
    __syncthreads();
    // Fold wire2: B[s][t2*3+t3][ih*4+jh]
    for (int e = t; e < 576; e += 1024) {
        int m = e / 144, r = e % 144;
        int t2 = r / 48; r %= 48;
        int t3 = r / 16, q = r % 16;
        int ih = q >> 2, jh = q & 3;
        float a00 = A[m][t3][(ih * 2 + 0) * 8 + jh * 2 + 0];
        float a01 = A[m][t3][(ih * 2 + 0) * 8 + jh * 2 + 1];
        float a10 = A[m][t3][(ih * 2 + 1) * 8 + jh * 2 + 0];
        float a11 = A[m][t3][(ih * 2 + 1) * 8 + jh * 2 + 1];
        B[m][t2 * 3 + t3][q] = (t2 == 0) ? a00 + a11
                             : (t2 == 1) ? a00 - a11 : a01 + a10;
    }
    __syncthreads();
    // Fold wire1: C1[s][t1*9+t2*3+t3][ih*2+jh]
    for (int e = t; e < 432; e += 1024) {
        int m = e / 108, r = e % 108;
        int t1 = r / 36; r %= 36;
        int t23 = r / 4, q = r % 4;
        int ih = q >> 1, jh = q & 1;
        float b00 = B[m][t23][(ih * 2 + 0) * 4 + jh * 2 + 0];
        float b01 = B[m][t23][(ih * 2 + 0) * 4 + jh * 2 + 1];
        float b10 = B[m][t23][(ih * 2 + 1) * 4 + jh * 2 + 0];
        float b11 = B[m][t23][(ih * 2 + 1) * 4 + jh * 2 + 1];
        C1[m][t1 * 9 + t23][q] = (t1 == 0) ? b00 + b11
                               : (t1 == 1) ? b00 - b11 : b01 + b10;
    }
    __syncthreads();
    // Fold wire0 + write padded tiles.  Scale: (1/64)^2 H-norm, (1/2)^4
    // half-angle basis.  lin_b difference folded into tabs[0][0][0].
    {
        const float scale = 1.f / 65536.f;
        float bias = lin_b[0] - lin_b[1];
        for (int e = t; e < 324; e += 1024) {
            int m = e / 81, r = e % 81;
            int t0 = r / 27, t123 = r % 27;
            const float* c = C1[m][t123];
            float v = (t0 == 0) ? c[0] + c[3] : (t0 == 1) ? c[0] - c[3]
                                              : c[1] + c[2];
            float val = v * scale;
            if (e == 0) val += bias;
            int t1 = t123 / 9, k = t123 % 9;
            tabs[m][t0 * 3 + t1][k] = val;
        }
    }
    __syncthreads();

    // ---- batch compute: identical to round-4's K2 loop ----
    float xs[16] = {xa.x, xa.y, xa.z, xa.w, xb.x, xb.y, xb.z, xb.w,
                    xc.x, xc.y, xc.z, xc.w, xd.x, xd.y, xd.z, xd.w};
    float d = 0.f;
    #pragma unroll
    for (int s = 0; s < 4; ++s) {
        const int b0 = ((s >> 1) << 3) + ((s & 1) << 1);
        // wires 0,1,2,3 of circuit s -> x indices b0, b0+1, b0+4, b0+5
        float C0, S0, C1v, S1, C2, S2, C3, S3;
        __sincosf(xs[b0],     &S0,  &C0);
        __sincosf(xs[b0 + 1], &S1,  &C1v);
        __sincosf(xs[b0 + 4], &S2,  &C2);
        __sincosf(xs[b0 + 5], &S3,  &C3);
        #pragma unroll
        for (int t0 = 0; t0 < 3; ++t0) {
            float acc = 0.f;
            #pragma unroll
            for (int t1 = 0; t1 < 3; ++t1) {
                const float* tp = &tabs[s][t0 * 3 + t1][0];
                float4 q0 = *(const float4*)tp;        // k0..k3
                float4 q1 = *(const float4*)(tp + 4);  // k4..k7
                float  k8 = tp[8];
                float u0 = fmaf(S3, q0.z, fmaf(C3, q0.y, q0.x));
                float u1 = fmaf(S3, q1.y, fmaf(C3, q1.x, q0.w));
                float u2 = fmaf(S3, k8,   fmaf(C3, q1.w, q1.z));
                float a1 = fmaf(S2, u2, fmaf(C2, u1, u0));
                acc = (t1 == 0) ? acc + a1
                    : (t1 == 1) ? fmaf(C1v, a1, acc)
                                : fmaf(S1,  a1, acc);
            }
            d = (t0 == 0) ? d + acc
              : (t0 == 1) ? fmaf(C0, acc, d)
                          : fmaf(S0, acc, d);
        }
    }

    if (b < nrows) {
        // bias already folded into tabs[0][0][0]; softmax over 2 = sigmoid
        float p0 = 1.f / (1.f + __expf(-d));
        *(float2*)(out + (size_t)b * 2) = make_float2(p0, 1.f - p0);
    }

    // grid-stride fallback (dead when grid covers nrows exactly)
    for (int row = b + gridDim.x * blockDim.x; row < nrows;
         row += gridDim.x * blockDim.x) {
        const float4* xq = (const float4*)(x + (size_t)row * 16);
        float4 ya = xq[0], yb = xq[1], yc = xq[2], yd = xq[3];
        float ys[16] = {ya.x, ya.y, ya.z, ya.w, yb.x, yb.y, yb.z, yb.w,
                        yc.x, yc.y, yc.z, yc.w, yd.x, yd.y, yd.z, yd.w};
        float dd = 0.f;
        #pragma unroll
        for (int s = 0; s < 4; ++s) {
            const int b0 = ((s >> 1) << 3) + ((s & 1) << 1);
            float C0, S0, C1v, S1, C2, S2, C3, S3;
            __sincosf(ys[b0],     &S0,  &C0);
            __sincosf(ys[b0 + 1], &S1,  &C1v);
            __sincosf(ys[b0 + 4], &S2,  &C2);
            __sincosf(ys[b0 + 5], &S3,  &C3);
            #pragma unroll
            for (int t0 = 0; t0 < 3; ++t0) {
                float acc = 0.f;
                #pragma unroll
                for (int t1 = 0; t1 < 3; ++t1) {
                    const float* tp = &tabs[s][t0 * 3 + t1][0];
                    float4 q0 = *(const float4*)tp;
                    float4 q1 = *(const float4*)(tp + 4);
                    float  k8 = tp[8];
                    float u0 = fmaf(S3, q0.z, fmaf(C3, q0.y, q0.x));
                    float u1 = fmaf(S3, q1.y, fmaf(C3, q1.x, q0.w));
                    float u2 = fmaf(S3, k8,   fmaf(C3, q1.w, q1.z));
                    float a1 = fmaf(S2, u2, fmaf(C2, u1, u0));
                    acc = (t1 == 0) ? acc + a1
                        : (t1 == 1) ? fmaf(C1v, a1, acc)
                                    : fmaf(S1,  a1, acc);
                }
                dd = (t0 == 0) ? dd + acc
                   : (t0 == 1) ? fmaf(C0, acc, dd)
                               : fmaf(S0, acc, dd);
            }
        }
        float p0 = 1.f / (1.f + __expf(-dd));
        *(float2*)(out + (size_t)row * 2) = make_float2(p0, 1.f - p0);
    }
}

extern "C" void kernel_launch(void* const* d_in, const int* in_sizes, int n_in,
                              void* d_out, int out_size, void* d_ws, size_t ws_size,
                              hipStream_t stream) {
    const float* x       = (const float*)d_in[0];
    const float* weights = (const float*)d_in[1];
    const float* lin_w   = (const float*)d_in[2];
    const float* lin_b   = (const float*)d_in[3];
    float* out = (float*)d_out;

    int nrows = in_sizes[0] / 16;
    int block = 1024;
    int grid = (nrows + block - 1) / block;
    if (grid < 1) grid = 1;
    fused_qcircuit<<<grid, block, 0, stream>>>(x, weights, lin_w, lin_b, out, nrows);
}